// Round 1
// 1180.755 us; speedup vs baseline: 1.0455x; 1.0455x over previous
//
#include <hip/hip_runtime.h>
#include <stdint.h>
#include <stddef.h>

// Problem constants
#define BSZ 64
#define MM  2048
#define DD  1024
#define HH  1024
#define RR  (BSZ * MM)   // 131072 rows of the big GEMM

typedef float  float4v  __attribute__((ext_vector_type(4)));
typedef float  float8v  __attribute__((ext_vector_type(8)));
typedef short  short4v  __attribute__((ext_vector_type(4)));
typedef short  short8v  __attribute__((ext_vector_type(8)));
typedef __bf16 bf16x4v  __attribute__((ext_vector_type(4)));
typedef __bf16 bf16x8v  __attribute__((ext_vector_type(8)));

__device__ __forceinline__ short8v cvt_f32x8_bf16(float4v lo, float4v hi) {
    float8v f;
    f[0] = lo[0]; f[1] = lo[1]; f[2] = lo[2]; f[3] = lo[3];
    f[4] = hi[0]; f[5] = hi[1]; f[6] = hi[2]; f[7] = hi[3];
    union { bf16x8v b; short8v s; } u;
    u.b = __builtin_convertvector(f, bf16x8v);   // v_cvt_pk_bf16_f32 x4
    return u.s;
}

// tanh(x) = sign(x) * (1 - 2e/(1+e)), e = exp(-2|x|). No overflow, ~6 VALU ops.
__device__ __forceinline__ float fast_tanh(float x) {
    float ax = __builtin_fabsf(x);
    float e  = __builtin_amdgcn_exp2f(ax * -2.88539008177792681f); // e^{-2ax}
    float r  = __builtin_amdgcn_rcpf(1.0f + e);
    float t  = __builtin_fmaf(-2.0f * e, r, 1.0f);
    return __builtin_copysignf(t, x);
}

// ---------------------------------------------------------------- cast Wm -> bf16
__global__ __launch_bounds__(256) void cast_wm_kernel(const float* __restrict__ wm,
                                                      short* __restrict__ out) {
    int i = (blockIdx.x * 256 + threadIdx.x) * 4;
    float4v f = *(const float4v*)(wm + i);
    union { bf16x4v b; short4v s; } u;
    u.b = __builtin_convertvector(f, bf16x4v);
    *(short4v*)(out + i) = u.s;
}

// ---------------------------------------------------------------- qproj (fp32 exact)
// qproj[b,h] = sum_d query[b,d]*Wq[h,d] + bq[h]
__global__ __launch_bounds__(256) void qproj_kernel(const float* __restrict__ query,
                                                    const float* __restrict__ Wq,
                                                    const float* __restrict__ bq,
                                                    float* __restrict__ qproj) {
    __shared__ __align__(16) float qs[DD];
    const int b = blockIdx.y;
    const int h = blockIdx.x * 256 + threadIdx.x;
    for (int i = threadIdx.x; i < DD; i += 256) qs[i] = query[b * DD + i];
    __syncthreads();
    const float4v* wrow = (const float4v*)(Wq + (size_t)h * DD);
    float acc = 0.0f;
#pragma unroll 4
    for (int d4 = 0; d4 < DD / 4; ++d4) {
        float4v w = wrow[d4];
        float4v q = *(const float4v*)(qs + d4 * 4);
        acc += w[0] * q[0] + w[1] * q[1] + w[2] * q[2] + w[3] * q[3];
    }
    qproj[b * HH + h] = acc + bq[h];
}

// ---------------------------------------------------------------- big fused GEMM
// attn[r] += sum_h tanh( (memory @ Wm^T)[r,h] + qproj[b,h] ) * v[h]
// 128x128 tile, BK=32, 4 waves (2x2), each wave 4x4 frags of 16x16x32 bf16 MFMA.
// A (memory) staged fp32 via global_load_lds; converted to bf16 at frag read.
//
// LDS XOR swizzle (T2, rule #21 both-sides): global_load_lds writes linearly
// (base + lane*16), so the swizzle is applied by pre-swizzling the per-lane
// GLOBAL source granule, and XOR-ing the same pattern on the ds_read side.
//   A rows are 128 B = 8 x 16B granules:  As[m][slot] = M[m][slot ^ (m&7)]
//   B rows are  64 B = 4 x 16B granules:  Bs[n][slot] = W[n][slot ^ ((n>>1)&3)]
//     (B uses (n>>1)&3, NOT n&3: n&1 already alternates the 16-bank half-row,
//      so XOR-ing bit0 of n would leave lanes 0/4/8/12 4-way colliding.)
// Bank check per 16-lane phase: all 8 (resp. 4+parity) granule groups covered,
// 2 lanes/bank = conflict-free (m136: 2-way is free).
__global__ __launch_bounds__(256) void gemm_attn_kernel(
    const float* __restrict__ memf, const short* __restrict__ wmbf,
    const float* __restrict__ qproj, const float* __restrict__ vvec,
    float* __restrict__ attn) {
    __shared__ __align__(16) float As[128 * 32];   // 16 KB fp32 [m][k], swizzled
    __shared__ __align__(16) short Bs[128 * 32];   // 8 KB bf16 [n][k], swizzled

    const int tid  = threadIdx.x;
    const int lane = tid & 63;
    const int wave = tid >> 6;
    const int wx = wave & 1, wy = wave >> 1;

    // XCD-aware swizzle: the 8 column-tiles of one row-tile land on one XCD
    // so the 512 KB A row-tile is served from that XCD's L2 after first touch.
    const int bi    = blockIdx.x;
    const int xcd   = bi & 7;
    const int idx   = bi >> 3;
    const int tileR = xcd * 128 + (idx >> 3);   // 0..1023
    const int tileC = idx & 7;                  // 0..7
    const int r0 = tileR * 128;
    const int h0 = tileC * 128;

    // Staging source pointers (global side is per-lane; LDS side uniform+lane*16)
    // Source column is PRE-SWIZZLED so the linear LDS write produces the
    // swizzled layout.
    const float* aptr[4];
#pragma unroll
    for (int j = 0; j < 4; ++j) {
        int i   = wave * 4 + j;
        int row = i * 8 + (lane >> 3);                  // row&7 == lane>>3
        int col = ((lane & 7) ^ (lane >> 3)) * 4;       // granule ^ (row&7)
        aptr[j] = memf + (size_t)(r0 + row) * DD + col;
    }
    const short* bptr[2];
#pragma unroll
    for (int j = 0; j < 2; ++j) {
        int i   = wave * 2 + j;
        int row = i * 16 + (lane >> 2);                 // (row>>1)&3 == (lane>>3)&3
        int col = ((lane & 3) ^ ((lane >> 3) & 3)) * 8; // granule ^ ((row>>1)&3)
        bptr[j] = wmbf + (size_t)(h0 + row) * DD + col;
    }

    float4v acc[4][4];
#pragma unroll
    for (int a = 0; a < 4; ++a)
#pragma unroll
        for (int b = 0; b < 4; ++b) acc[a][b] = (float4v)0.0f;

    const int c  = lane & 15;
    const int g  = lane >> 4;

    for (int kt = 0; kt < DD / 32; ++kt) {
        __syncthreads();
#pragma unroll
        for (int j = 0; j < 4; ++j) {
            __builtin_amdgcn_global_load_lds(
                (const __attribute__((address_space(1))) void*)(aptr[j]),
                (__attribute__((address_space(3))) void*)((char*)As + (wave * 4 + j) * 1024),
                16, 0, 0);
            aptr[j] += 32;
        }
#pragma unroll
        for (int j = 0; j < 2; ++j) {
            __builtin_amdgcn_global_load_lds(
                (const __attribute__((address_space(1))) void*)(bptr[j]),
                (__attribute__((address_space(3))) void*)((char*)Bs + (wave * 2 + j) * 1024),
                16, 0, 0);
            bptr[j] += 32;
        }
        __syncthreads();

        short8v bfr[4];
#pragma unroll
        for (int nf = 0; nf < 4; ++nf) {
            int n  = wx * 64 + nf * 16 + c;
            int gb = g ^ ((n >> 1) & 3);                 // swizzled granule
            bfr[nf] = *(const short8v*)(Bs + n * 32 + gb * 8);
        }
#pragma unroll
        for (int mf = 0; mf < 4; ++mf) {
            int m  = wy * 64 + mf * 16 + c;
            int sw = m & 7;
            int gl = (g * 2) ^ sw;                       // lo granule (16B)
            int gh = (g * 2 + 1) ^ sw;                   // hi granule (16B)
            float4v lo = *(const float4v*)(As + m * 32 + gl * 4);
            float4v hi = *(const float4v*)(As + m * 32 + gh * 4);
            short8v afr = cvt_f32x8_bf16(lo, hi);
#pragma unroll
            for (int nf = 0; nf < 4; ++nf)
                acc[mf][nf] = __builtin_amdgcn_mfma_f32_16x16x32_bf16(
                    afr, bfr[nf], acc[mf][nf], 0, 0, 0);
        }
    }

    // Epilogue: tanh(acc + qproj) * v, reduce over h (columns), atomic into attn.
    const int b = tileR >> 4;   // 16 row-tiles per batch (2048/128)
    float vv[4], qp[4];
#pragma unroll
    for (int nf = 0; nf < 4; ++nf) {
        int h   = h0 + wx * 64 + nf * 16 + c;
        vv[nf] = vvec[h];
        qp[nf] = qproj[b * HH + h];
    }
    float rs[4][4];
#pragma unroll
    for (int mf = 0; mf < 4; ++mf)
#pragma unroll
        for (int r = 0; r < 4; ++r) rs[mf][r] = 0.0f;
#pragma unroll
    for (int mf = 0; mf < 4; ++mf)
#pragma unroll
        for (int nf = 0; nf < 4; ++nf)
#pragma unroll
            for (int r = 0; r < 4; ++r)
                rs[mf][r] += fast_tanh(acc[mf][nf][r] + qp[nf]) * vv[nf];

    // C/D layout: col = lane&15 (h), row = (lane>>4)*4 + reg (memory row).
    // Reduce the 16 columns held across lanes (xor over low 4 lane bits).
#pragma unroll
    for (int mf = 0; mf < 4; ++mf)
#pragma unroll
        for (int r = 0; r < 4; ++r) {
            float s = rs[mf][r];
            s += __shfl_xor(s, 1);
            s += __shfl_xor(s, 2);
            s += __shfl_xor(s, 4);
            s += __shfl_xor(s, 8);
            if (c == 0)
                atomicAdd(attn + (r0 + wy * 64 + mf * 16 + g * 4 + r), s);
        }
}

// ---------------------------------------------------------------- softmax over M
__global__ __launch_bounds__(256) void softmax_kernel(const float* __restrict__ attn,
                                                      float* __restrict__ wout) {
    const int b = blockIdx.x, tid = threadIdx.x;
    __shared__ float red[8];
    float a[8];
    float mx = -1e30f;
#pragma unroll
    for (int i = 0; i < 8; ++i) {
        a[i] = attn[b * MM + i * 256 + tid];
        mx = fmaxf(mx, a[i]);
    }
#pragma unroll
    for (int off = 1; off < 64; off <<= 1) mx = fmaxf(mx, __shfl_xor(mx, off));
    if ((tid & 63) == 0) red[tid >> 6] = mx;
    __syncthreads();
    mx = fmaxf(fmaxf(red[0], red[1]), fmaxf(red[2], red[3]));
    float s = 0.0f;
#pragma unroll
    for (int i = 0; i < 8; ++i) {
        a[i] = __builtin_amdgcn_exp2f((a[i] - mx) * 1.4426950408889634f);
        s += a[i];
    }
#pragma unroll
    for (int off = 1; off < 64; off <<= 1) s += __shfl_xor(s, off);
    if ((tid & 63) == 0) red[4 + (tid >> 6)] = s;
    __syncthreads();
    s = red[4] + red[5] + red[6] + red[7];
    float inv = 1.0f / s;
#pragma unroll
    for (int i = 0; i < 8; ++i) wout[b * MM + i * 256 + tid] = a[i] * inv;
}

// ---------------------------------------------------------------- weighted memory
// out2[b,d] = sum_m w[b,m] * memory[b,m,d]; m split x4, atomic accumulate.
__global__ __launch_bounds__(256) void wmem_kernel(const float* __restrict__ mem,
                                                   const float* __restrict__ w,
                                                   float* __restrict__ out2) {
    const int b  = blockIdx.z;
    const int d  = blockIdx.x * 256 + threadIdx.x;
    const int m0 = blockIdx.y * 512;
    __shared__ float wsh[512];
    for (int i = threadIdx.x; i < 512; i += 256) wsh[i] = w[b * MM + m0 + i];
    __syncthreads();
    const float* mp = mem + ((size_t)(b * MM + m0)) * DD + d;
    float acc = 0.0f;
#pragma unroll 8
    for (int m = 0; m < 512; ++m)
        acc = __builtin_fmaf(wsh[m], mp[(size_t)m * DD], acc);
    atomicAdd(out2 + b * DD + d, acc);
}

// ---------------------------------------------------------------- launcher
extern "C" void kernel_launch(void* const* d_in, const int* in_sizes, int n_in,
                              void* d_out, int out_size, void* d_ws, size_t ws_size,
                              hipStream_t stream) {
    const float* query  = (const float*)d_in[0];
    const float* memory = (const float*)d_in[1];
    const float* Wq     = (const float*)d_in[2];
    const float* bq     = (const float*)d_in[3];
    const float* Wm     = (const float*)d_in[4];
    const float* v      = (const float*)d_in[5];

    float* out      = (float*)d_out;
    float* wout     = out;                       // weights [64,1,2048]
    float* wmem_out = out + BSZ * MM;            // weighted_memory [64,1,1024]

    char*  ws    = (char*)d_ws;
    float* qproj = (float*)ws;                   // 256 KB
    float* attn  = (float*)(ws + 262144);        // 512 KB
    short* wmbf  = (short*)(ws + 786432);        // 2 MB  (total 2.75 MB of ws)

    hipMemsetAsync(attn, 0, (size_t)RR * sizeof(float), stream);
    hipMemsetAsync(d_out, 0, (size_t)out_size * sizeof(float), stream);

    cast_wm_kernel<<<HH * DD / (256 * 4), 256, 0, stream>>>(Wm, wmbf);
    qproj_kernel<<<dim3(HH / 256, BSZ), 256, 0, stream>>>(query, Wq, bq, qproj);
    gemm_attn_kernel<<<(RR / 128) * (HH / 128), 256, 0, stream>>>(memory, wmbf, qproj, v, attn);
    softmax_kernel<<<BSZ, 256, 0, stream>>>(attn, wout);
    wmem_kernel<<<dim3(DD / 256, 4, BSZ), 256, 0, stream>>>(memory, wout, wmem_out);
}

// Round 2
// 1121.708 us; speedup vs baseline: 1.1006x; 1.0526x over previous
//
#include <hip/hip_runtime.h>
#include <stdint.h>
#include <stddef.h>

// Problem constants
#define BSZ 64
#define MM  2048
#define DD  1024
#define HH  1024
#define RR  (BSZ * MM)   // 131072 rows of the big GEMM

typedef float  float4v  __attribute__((ext_vector_type(4)));
typedef float  float8v  __attribute__((ext_vector_type(8)));
typedef short  short4v  __attribute__((ext_vector_type(4)));
typedef short  short8v  __attribute__((ext_vector_type(8)));
typedef __bf16 bf16x4v  __attribute__((ext_vector_type(4)));
typedef __bf16 bf16x8v  __attribute__((ext_vector_type(8)));

#define AS1 __attribute__((address_space(1)))
#define AS3 __attribute__((address_space(3)))

__device__ __forceinline__ short8v cvt_f32x8_bf16(float4v lo, float4v hi) {
    float8v f;
    f[0] = lo[0]; f[1] = lo[1]; f[2] = lo[2]; f[3] = lo[3];
    f[4] = hi[0]; f[5] = hi[1]; f[6] = hi[2]; f[7] = hi[3];
    union { bf16x8v b; short8v s; } u;
    u.b = __builtin_convertvector(f, bf16x8v);   // v_cvt_pk_bf16_f32 x4
    return u.s;
}

// tanh(x) = sign(x) * (1 - 2e/(1+e)), e = exp(-2|x|). No overflow, ~6 VALU ops.
__device__ __forceinline__ float fast_tanh(float x) {
    float ax = __builtin_fabsf(x);
    float e  = __builtin_amdgcn_exp2f(ax * -2.88539008177792681f); // e^{-2ax}
    float r  = __builtin_amdgcn_rcpf(1.0f + e);
    float t  = __builtin_fmaf(-2.0f * e, r, 1.0f);
    return __builtin_copysignf(t, x);
}

// ---------------------------------------------------------------- cast Wm -> bf16
__global__ __launch_bounds__(256) void cast_wm_kernel(const float* __restrict__ wm,
                                                      short* __restrict__ out) {
    int i = (blockIdx.x * 256 + threadIdx.x) * 4;
    float4v f = *(const float4v*)(wm + i);
    union { bf16x4v b; short4v s; } u;
    u.b = __builtin_convertvector(f, bf16x4v);
    *(short4v*)(out + i) = u.s;
}

// ---------------------------------------------------------------- qproj (fp32 exact)
__global__ __launch_bounds__(256) void qproj_kernel(const float* __restrict__ query,
                                                    const float* __restrict__ Wq,
                                                    const float* __restrict__ bq,
                                                    float* __restrict__ qproj) {
    __shared__ __align__(16) float qs[DD];
    const int b = blockIdx.y;
    const int h = blockIdx.x * 256 + threadIdx.x;
    for (int i = threadIdx.x; i < DD; i += 256) qs[i] = query[b * DD + i];
    __syncthreads();
    const float4v* wrow = (const float4v*)(Wq + (size_t)h * DD);
    float acc = 0.0f;
#pragma unroll 4
    for (int d4 = 0; d4 < DD / 4; ++d4) {
        float4v w = wrow[d4];
        float4v q = *(const float4v*)(qs + d4 * 4);
        acc += w[0] * q[0] + w[1] * q[1] + w[2] * q[2] + w[3] * q[3];
    }
    qproj[b * HH + h] = acc + bq[h];
}

// ---------------------------------------------------------------- big fused GEMM
// attn[r] += sum_h tanh( (memory @ Wm^T)[r,h] + qproj[b,h] ) * v[h]
//
// 256x256 tile, BK=32, 8 waves (WARPS_M=4 x WARPS_N=2), per-wave 64x128 output
// (4 mf x 8 nf frags of 16x16x32 bf16 MFMA). 4-phase K-step schedule (T3+T4):
// per phase {ds_read subtile | issue prefetch gload_lds | s_barrier |
// lgkmcnt(0)+sched_barrier | setprio(1) 8xMFMA setprio(0) | s_barrier}.
// vmcnt(0) only ONCE per K-tile (phase 3), ~3 phases after the last prefetch
// issue -> loads stay in flight across barriers (counted-vmcnt pattern).
// Double-buffered LDS: A fp32 2x32KB + B bf16 2x16KB = 96KB dynamic.
//
// LDS XOR swizzle (T2, rule #21 both-sides, verified round 1):
//   A rows 128B = 8x16B granules:  As[m][slot] = M[m][slot ^ (m&7)]
//   B rows  64B = 4x16B granules:  Bs[n][slot] = W[n][slot ^ ((n>>1)&3)]
// Applied by pre-swizzling the per-lane GLOBAL source (gload_lds writes
// linearly) and XOR-ing identically on the ds_read side.
__global__ __launch_bounds__(512, 2) void gemm_attn_kernel(
    const float* __restrict__ memf, const short* __restrict__ wmbf,
    const float* __restrict__ qproj, const float* __restrict__ vvec,
    float* __restrict__ attn) {
    extern __shared__ __align__(16) char smem[];
    float* As = (float*)smem;               // 2 bufs x 8192 fp32  (byte 0, 65536)
    short* Bs = (short*)(smem + 65536);     // 2 bufs x 8192 bf16  (byte 65536..98303)

    const int tid  = threadIdx.x;
    const int lane = tid & 63;
    const int wave = tid >> 6;       // 0..7
    const int wm   = wave >> 1;      // 0..3  (M split)
    const int wn   = wave & 1;       // 0..1  (N split)

    // XCD-aware swizzle: nwg=2048, 256 contiguous wgids per XCD; tileC fastest
    // so the 4 column-tiles of one 1MB A row-tile run together on one XCD L2.
    const int bi    = blockIdx.x;
    const int wg    = (bi & 7) * 256 + (bi >> 3);
    const int tileR = wg >> 2;       // 0..511
    const int tileC = wg & 3;        // 0..3
    const int r0 = tileR * 256;
    const int h0 = tileC * 256;

    // ---- staging source pointers (global side per-lane, pre-swizzled) ----
    // A: 32 wave-instrs of 1KB; wave w instr j covers rows (w*4+j)*8 .. +7
    const float* aptr[4];
#pragma unroll
    for (int j = 0; j < 4; ++j) {
        int row = (wave * 4 + j) * 8 + (lane >> 3);     // row&7 == lane>>3
        int col = ((lane & 7) ^ (lane >> 3)) * 4;       // granule ^ (row&7)
        aptr[j] = memf + (size_t)(r0 + row) * DD + col;
    }
    // B: 16 wave-instrs of 1KB; wave w instr j covers rows (w*2+j)*16 .. +15
    const short* bptr[2];
#pragma unroll
    for (int j = 0; j < 2; ++j) {
        int row = (wave * 2 + j) * 16 + (lane >> 2);    // (row>>1)&3 == (lane>>3)&3
        int col = ((lane & 3) ^ ((lane >> 3) & 3)) * 8;
        bptr[j] = wmbf + (size_t)(h0 + row) * DD + col;
    }

    const int c = lane & 15;
    const int g = lane >> 4;

    // ---- fragment read offsets (swizzled, element units) ----
    int offAlo[4], offAhi[4];
#pragma unroll
    for (int mf = 0; mf < 4; ++mf) {
        int m  = wm * 64 + mf * 16 + c;
        int sw = m & 7;
        offAlo[mf] = m * 32 + ((g * 2) ^ sw) * 4;
        offAhi[mf] = m * 32 + ((g * 2 + 1) ^ sw) * 4;
    }
    int offB[8];
#pragma unroll
    for (int nf = 0; nf < 8; ++nf) {
        int n = wn * 128 + nf * 16 + c;
        offB[nf] = n * 32 + (g ^ ((n >> 1) & 3)) * 8;
    }

    float4v acc[4][8];
#pragma unroll
    for (int mf = 0; mf < 4; ++mf)
#pragma unroll
        for (int nf = 0; nf < 8; ++nf) acc[mf][nf] = (float4v)0.0f;

    // ---- prologue: stage K-tile 0 into buf 0 ----
#pragma unroll
    for (int j = 0; j < 4; ++j) {
        __builtin_amdgcn_global_load_lds(
            (const AS1 void*)aptr[j],
            (AS3 void*)(smem + (wave * 4 + j) * 1024), 16, 0, 0);
        aptr[j] += 32;
    }
#pragma unroll
    for (int j = 0; j < 2; ++j) {
        __builtin_amdgcn_global_load_lds(
            (const AS1 void*)bptr[j],
            (AS3 void*)(smem + 65536 + (wave * 2 + j) * 1024), 16, 0, 0);
        bptr[j] += 32;
    }
    asm volatile("s_waitcnt vmcnt(0)" ::: "memory");
    asm volatile("s_barrier" ::: "memory");

    short8v afr[4], bfr[2];

    for (int t = 0; t < 32; ++t) {
        const int cur = t & 1;
        const int nxt = cur ^ 1;
        const float* Ab = As + cur * 8192;
        const short* Bb = Bs + cur * 8192;
        char* AnB = smem + nxt * 32768;
        char* BnB = smem + 65536 + nxt * 16384;
        const bool pf = (t < 31);

#pragma unroll
        for (int p = 0; p < 4; ++p) {
            // phase ds_reads (buf cur)
            float4v alo[4], ahi[4];
            if (p == 0) {
#pragma unroll
                for (int mf = 0; mf < 4; ++mf) {
                    alo[mf] = *(const float4v*)(Ab + offAlo[mf]);
                    ahi[mf] = *(const float4v*)(Ab + offAhi[mf]);
                }
            }
            bfr[0] = *(const short8v*)(Bb + offB[2 * p]);
            bfr[1] = *(const short8v*)(Bb + offB[2 * p + 1]);

            // prefetch issue for K-tile t+1 (buf nxt); never waited mid-tile
            if (p == 0 && pf) {
                __builtin_amdgcn_global_load_lds((const AS1 void*)aptr[0],
                    (AS3 void*)(AnB + (wave * 4 + 0) * 1024), 16, 0, 0);
                __builtin_amdgcn_global_load_lds((const AS1 void*)aptr[1],
                    (AS3 void*)(AnB + (wave * 4 + 1) * 1024), 16, 0, 0);
                aptr[0] += 32; aptr[1] += 32;
            } else if (p == 1 && pf) {
                __builtin_amdgcn_global_load_lds((const AS1 void*)aptr[2],
                    (AS3 void*)(AnB + (wave * 4 + 2) * 1024), 16, 0, 0);
                __builtin_amdgcn_global_load_lds((const AS1 void*)aptr[3],
                    (AS3 void*)(AnB + (wave * 4 + 3) * 1024), 16, 0, 0);
                aptr[2] += 32; aptr[3] += 32;
            } else if (p == 2 && pf) {
                __builtin_amdgcn_global_load_lds((const AS1 void*)bptr[0],
                    (AS3 void*)(BnB + (wave * 2 + 0) * 1024), 16, 0, 0);
                __builtin_amdgcn_global_load_lds((const AS1 void*)bptr[1],
                    (AS3 void*)(BnB + (wave * 2 + 1) * 1024), 16, 0, 0);
                bptr[0] += 32; bptr[1] += 32;
            }

            asm volatile("s_barrier" ::: "memory");
            asm volatile("s_waitcnt lgkmcnt(0)" ::: "memory");
            __builtin_amdgcn_sched_barrier(0);       // rule #18

            if (p == 0) {
#pragma unroll
                for (int mf = 0; mf < 4; ++mf)
                    afr[mf] = cvt_f32x8_bf16(alo[mf], ahi[mf]);
            }

            __builtin_amdgcn_s_setprio(1);
#pragma unroll
            for (int mf = 0; mf < 4; ++mf) {
                acc[mf][2 * p] = __builtin_amdgcn_mfma_f32_16x16x32_bf16(
                    afr[mf], bfr[0], acc[mf][2 * p], 0, 0, 0);
                acc[mf][2 * p + 1] = __builtin_amdgcn_mfma_f32_16x16x32_bf16(
                    afr[mf], bfr[1], acc[mf][2 * p + 1], 0, 0, 0);
            }
            __builtin_amdgcn_s_setprio(0);

            // once per K-tile: ensure next buf's DMA landed (own 6 loads),
            // then barrier makes it collective.
            if (p == 3) asm volatile("s_waitcnt vmcnt(0)" ::: "memory");
            asm volatile("s_barrier" ::: "memory");
        }
    }

    // ---- epilogue: tanh(acc + qproj) * v, reduce over h, atomic into attn ----
    const int b = tileR >> 3;   // 8 row-tiles per batch (2048/256)
    float vv[8], qp[8];
#pragma unroll
    for (int nf = 0; nf < 8; ++nf) {
        int h  = h0 + wn * 128 + nf * 16 + c;
        vv[nf] = vvec[h];
        qp[nf] = qproj[b * HH + h];
    }
#pragma unroll
    for (int mf = 0; mf < 4; ++mf)
#pragma unroll
        for (int r = 0; r < 4; ++r) {
            float s = 0.0f;
#pragma unroll
            for (int nf = 0; nf < 8; ++nf)
                s += fast_tanh(acc[mf][nf][r] + qp[nf]) * vv[nf];
            // C/D layout: col = lane&15 (h), row = (lane>>4)*4 + reg (m row)
            s += __shfl_xor(s, 1);
            s += __shfl_xor(s, 2);
            s += __shfl_xor(s, 4);
            s += __shfl_xor(s, 8);
            if (c == 0)
                atomicAdd(attn + (r0 + wm * 64 + mf * 16 + g * 4 + r), s);
        }
}

// ---------------------------------------------------------------- softmax over M
__global__ __launch_bounds__(256) void softmax_kernel(const float* __restrict__ attn,
                                                      float* __restrict__ wout) {
    const int b = blockIdx.x, tid = threadIdx.x;
    __shared__ float red[8];
    float a[8];
    float mx = -1e30f;
#pragma unroll
    for (int i = 0; i < 8; ++i) {
        a[i] = attn[b * MM + i * 256 + tid];
        mx = fmaxf(mx, a[i]);
    }
#pragma unroll
    for (int off = 1; off < 64; off <<= 1) mx = fmaxf(mx, __shfl_xor(mx, off));
    if ((tid & 63) == 0) red[tid >> 6] = mx;
    __syncthreads();
    mx = fmaxf(fmaxf(red[0], red[1]), fmaxf(red[2], red[3]));
    float s = 0.0f;
#pragma unroll
    for (int i = 0; i < 8; ++i) {
        a[i] = __builtin_amdgcn_exp2f((a[i] - mx) * 1.4426950408889634f);
        s += a[i];
    }
#pragma unroll
    for (int off = 1; off < 64; off <<= 1) s += __shfl_xor(s, off);
    if ((tid & 63) == 0) red[4 + (tid >> 6)] = s;
    __syncthreads();
    s = red[4] + red[5] + red[6] + red[7];
    float inv = 1.0f / s;
#pragma unroll
    for (int i = 0; i < 8; ++i) wout[b * MM + i * 256 + tid] = a[i] * inv;
}

// ---------------------------------------------------------------- weighted memory
// out2[b,d] = sum_m w[b,m] * memory[b,m,d]; m split x8, float4 loads (G13),
// atomic accumulate.
__global__ __launch_bounds__(256) void wmem_kernel(const float* __restrict__ mem,
                                                   const float* __restrict__ w,
                                                   float* __restrict__ out2) {
    const int m0 = blockIdx.x * 256;
    const int b  = blockIdx.y;
    __shared__ float wsh[256];
    wsh[threadIdx.x] = w[b * MM + m0 + threadIdx.x];
    __syncthreads();
    const float4v* mp = (const float4v*)(mem + ((size_t)(b * MM + m0)) * DD)
                        + threadIdx.x;
    float4v acc = (float4v)0.0f;
#pragma unroll 8
    for (int m = 0; m < 256; ++m) {
        float wv = wsh[m];
        float4v x = mp[(size_t)m * 256];
        acc[0] = __builtin_fmaf(wv, x[0], acc[0]);
        acc[1] = __builtin_fmaf(wv, x[1], acc[1]);
        acc[2] = __builtin_fmaf(wv, x[2], acc[2]);
        acc[3] = __builtin_fmaf(wv, x[3], acc[3]);
    }
    float* o = out2 + b * DD + threadIdx.x * 4;
    atomicAdd(o + 0, acc[0]);
    atomicAdd(o + 1, acc[1]);
    atomicAdd(o + 2, acc[2]);
    atomicAdd(o + 3, acc[3]);
}

// ---------------------------------------------------------------- launcher
extern "C" void kernel_launch(void* const* d_in, const int* in_sizes, int n_in,
                              void* d_out, int out_size, void* d_ws, size_t ws_size,
                              hipStream_t stream) {
    const float* query  = (const float*)d_in[0];
    const float* memory = (const float*)d_in[1];
    const float* Wq     = (const float*)d_in[2];
    const float* bq     = (const float*)d_in[3];
    const float* Wm     = (const float*)d_in[4];
    const float* v      = (const float*)d_in[5];

    float* out      = (float*)d_out;
    float* wout     = out;                       // weights [64,1,2048]
    float* wmem_out = out + BSZ * MM;            // weighted_memory [64,1,1024]

    char*  ws    = (char*)d_ws;
    float* qproj = (float*)ws;                   // 256 KB
    float* attn  = (float*)(ws + 262144);        // 512 KB
    short* wmbf  = (short*)(ws + 786432);        // 2 MB  (total 2.75 MB of ws)

    static bool attr_done = false;
    if (!attr_done) {
        hipFuncSetAttribute((const void*)gemm_attn_kernel,
                            hipFuncAttributeMaxDynamicSharedMemorySize, 98304);
        attr_done = true;
    }

    hipMemsetAsync(attn, 0, (size_t)RR * sizeof(float), stream);
    hipMemsetAsync(d_out, 0, (size_t)out_size * sizeof(float), stream);

    cast_wm_kernel<<<HH * DD / (256 * 4), 256, 0, stream>>>(Wm, wmbf);
    qproj_kernel<<<dim3(HH / 256, BSZ), 256, 0, stream>>>(query, Wq, bq, qproj);
    gemm_attn_kernel<<<(RR / 256) * (HH / 256), 512, 98304, stream>>>(memory, wmbf, qproj, v, attn);
    softmax_kernel<<<BSZ, 256, 0, stream>>>(attn, wout);
    wmem_kernel<<<dim3(MM / 256, BSZ), 256, 0, stream>>>(memory, wout, wmem_out);
}

// Round 3
// 1052.537 us; speedup vs baseline: 1.1729x; 1.0657x over previous
//
#include <hip/hip_runtime.h>
#include <stdint.h>
#include <stddef.h>

// Problem constants
#define BSZ 64
#define MM  2048
#define DD  1024
#define HH  1024
#define RR  (BSZ * MM)   // 131072 rows of the big GEMM

typedef float  float4v  __attribute__((ext_vector_type(4)));
typedef float  float8v  __attribute__((ext_vector_type(8)));
typedef short  short4v  __attribute__((ext_vector_type(4)));
typedef short  short8v  __attribute__((ext_vector_type(8)));
typedef __bf16 bf16x4v  __attribute__((ext_vector_type(4)));
typedef __bf16 bf16x8v  __attribute__((ext_vector_type(8)));

#define AS1 __attribute__((address_space(1)))
#define AS3 __attribute__((address_space(3)))

__device__ __forceinline__ short8v cvt_f32x8_bf16(float4v lo, float4v hi) {
    float8v f;
    f[0] = lo[0]; f[1] = lo[1]; f[2] = lo[2]; f[3] = lo[3];
    f[4] = hi[0]; f[5] = hi[1]; f[6] = hi[2]; f[7] = hi[3];
    union { bf16x8v b; short8v s; } u;
    u.b = __builtin_convertvector(f, bf16x8v);   // v_cvt_pk_bf16_f32 x4
    return u.s;
}

// tanh(x) = sign(x) * (1 - 2e/(1+e)), e = exp(-2|x|). No overflow, ~6 VALU ops.
__device__ __forceinline__ float fast_tanh(float x) {
    float ax = __builtin_fabsf(x);
    float e  = __builtin_amdgcn_exp2f(ax * -2.88539008177792681f); // e^{-2ax}
    float r  = __builtin_amdgcn_rcpf(1.0f + e);
    float t  = __builtin_fmaf(-2.0f * e, r, 1.0f);
    return __builtin_copysignf(t, x);
}

// ---------------------------------------------------------------- cast Wm -> bf16
__global__ __launch_bounds__(256) void cast_wm_kernel(const float* __restrict__ wm,
                                                      short* __restrict__ out) {
    int i = (blockIdx.x * 256 + threadIdx.x) * 4;
    float4v f = *(const float4v*)(wm + i);
    union { bf16x4v b; short4v s; } u;
    u.b = __builtin_convertvector(f, bf16x4v);
    *(short4v*)(out + i) = u.s;
}

// ---------------------------------------------------------------- qproj (fp32 exact)
__global__ __launch_bounds__(256) void qproj_kernel(const float* __restrict__ query,
                                                    const float* __restrict__ Wq,
                                                    const float* __restrict__ bq,
                                                    float* __restrict__ qproj) {
    __shared__ __align__(16) float qs[DD];
    const int b = blockIdx.y;
    const int h = blockIdx.x * 256 + threadIdx.x;
    for (int i = threadIdx.x; i < DD; i += 256) qs[i] = query[b * DD + i];
    __syncthreads();
    const float4v* wrow = (const float4v*)(Wq + (size_t)h * DD);
    float acc = 0.0f;
#pragma unroll 4
    for (int d4 = 0; d4 < DD / 4; ++d4) {
        float4v w = wrow[d4];
        float4v q = *(const float4v*)(qs + d4 * 4);
        acc += w[0] * q[0] + w[1] * q[1] + w[2] * q[2] + w[3] * q[3];
    }
    qproj[b * HH + h] = acc + bq[h];
}

// ---------------------------------------------------------------- big fused GEMM
// attn[r] += sum_h tanh( (memory @ Wm^T)[r,h] + qproj[b,h] ) * v[h]
//
// 256x256 tile, BK=32, 8 waves (4Mx2N), per-wave 64x128 (4mf x 8nf of
// 16x16x32 bf16 MFMA). 4-phase K-step schedule (T3).
//
// T4 counted vmcnt, prefetch depth 2, TRIPLE-buffered LDS (144 KB):
//   during tile t issue the 6 gload_lds for tile t+2 (phases 0/1/2);
//   at end of tile t wait vmcnt(6): drains tile t+1's loads (issued a full
//   K-tile ~1500+cy ago -> latency fully hidden) and leaves t+2's 6 in
//   flight. vmcnt reaches 0 only in the loop tail (t>=30).
// Race audit: reads of buf b retire (lgkmcnt(0) before end-of-tile barrier)
// one full tile before buf b's next-life DMA is issued; vmcnt(6)+barrier at
// tile end makes buf t+1 collectively visible before any wave reads it.
//
// LDS XOR swizzle (T2, both-sides, verified round 1):
//   A rows 128B = 8x16B granules:  As[m][slot] = M[m][slot ^ (m&7)]
//   B rows  64B = 4x16B granules:  Bs[n][slot] = W[n][slot ^ ((n>>1)&3)]
__global__ __launch_bounds__(512, 2) void gemm_attn_kernel(
    const float* __restrict__ memf, const short* __restrict__ wmbf,
    const float* __restrict__ qproj, const float* __restrict__ vvec,
    float* __restrict__ attn) {
    extern __shared__ __align__(16) char smem[];
    // A: 3 bufs x 32 KB at byte 0; B: 3 bufs x 16 KB at byte 98304. 144 KB.

    const int tid  = threadIdx.x;
    const int lane = tid & 63;
    const int wave = tid >> 6;       // 0..7
    const int wm   = wave >> 1;      // 0..3  (M split)
    const int wn   = wave & 1;       // 0..1  (N split)

    // XCD-aware swizzle: nwg=2048, 256 contiguous wgids per XCD; tileC fastest
    // so the 4 column-tiles of one 1MB A row-tile run together on one XCD L2.
    const int bi    = blockIdx.x;
    const int wg    = (bi & 7) * 256 + (bi >> 3);
    const int tileR = wg >> 2;       // 0..511
    const int tileC = wg & 3;        // 0..3
    const int r0 = tileR * 256;
    const int h0 = tileC * 256;

    // ---- staging source pointers (global side per-lane, pre-swizzled) ----
    const float* aptr[4];
#pragma unroll
    for (int j = 0; j < 4; ++j) {
        int row = (wave * 4 + j) * 8 + (lane >> 3);     // row&7 == lane>>3
        int col = ((lane & 7) ^ (lane >> 3)) * 4;       // granule ^ (row&7)
        aptr[j] = memf + (size_t)(r0 + row) * DD + col;
    }
    const short* bptr[2];
#pragma unroll
    for (int j = 0; j < 2; ++j) {
        int row = (wave * 2 + j) * 16 + (lane >> 2);    // (row>>1)&3 == (lane>>3)&3
        int col = ((lane & 3) ^ ((lane >> 3) & 3)) * 8;
        bptr[j] = wmbf + (size_t)(h0 + row) * DD + col;
    }

    const int c = lane & 15;
    const int g = lane >> 4;

    // ---- fragment read offsets (swizzled, element units) ----
    int offAlo[4], offAhi[4];
#pragma unroll
    for (int mf = 0; mf < 4; ++mf) {
        int m  = wm * 64 + mf * 16 + c;
        int sw = m & 7;
        offAlo[mf] = m * 32 + ((g * 2) ^ sw) * 4;
        offAhi[mf] = m * 32 + ((g * 2 + 1) ^ sw) * 4;
    }
    int offB[8];
#pragma unroll
    for (int nf = 0; nf < 8; ++nf) {
        int n = wn * 128 + nf * 16 + c;
        offB[nf] = n * 32 + (g ^ ((n >> 1) & 3)) * 8;
    }

    float4v acc[4][8];
#pragma unroll
    for (int mf = 0; mf < 4; ++mf)
#pragma unroll
        for (int nf = 0; nf < 8; ++nf) acc[mf][nf] = (float4v)0.0f;

    // ---- prologue: stage K-tiles 0 and 1 into bufs 0 and 1 ----
#pragma unroll
    for (int t0 = 0; t0 < 2; ++t0) {
#pragma unroll
        for (int j = 0; j < 4; ++j) {
            __builtin_amdgcn_global_load_lds(
                (const AS1 void*)aptr[j],
                (AS3 void*)(smem + t0 * 32768 + (wave * 4 + j) * 1024), 16, 0, 0);
            aptr[j] += 32;
        }
#pragma unroll
        for (int j = 0; j < 2; ++j) {
            __builtin_amdgcn_global_load_lds(
                (const AS1 void*)bptr[j],
                (AS3 void*)(smem + 98304 + t0 * 16384 + (wave * 2 + j) * 1024), 16, 0, 0);
            bptr[j] += 32;
        }
    }
    asm volatile("s_waitcnt vmcnt(6)" ::: "memory");   // tile-0 loads done
    asm volatile("s_barrier" ::: "memory");

    short8v afr[4], bfr[2];
    int cur = 0;

    for (int t = 0; t < 32; ++t) {
        const float* Ab = (const float*)(smem + cur * 32768);
        const short* Bb = (const short*)(smem + 98304 + cur * 16384);
        int nx2 = cur + 2; if (nx2 >= 3) nx2 -= 3;     // buf for tile t+2
        char* AnB = smem + nx2 * 32768;
        char* BnB = smem + 98304 + nx2 * 16384;
        const bool pf = (t < 30);

#pragma unroll
        for (int p = 0; p < 4; ++p) {
            // phase ds_reads (buf cur)
            float4v alo[4], ahi[4];
            if (p == 0) {
#pragma unroll
                for (int mf = 0; mf < 4; ++mf) {
                    alo[mf] = *(const float4v*)(Ab + offAlo[mf]);
                    ahi[mf] = *(const float4v*)(Ab + offAhi[mf]);
                }
            }
            bfr[0] = *(const short8v*)(Bb + offB[2 * p]);
            bfr[1] = *(const short8v*)(Bb + offB[2 * p + 1]);

            // prefetch issue for K-tile t+2 (buf nx2); waited only via
            // counted vmcnt one full tile later.
            if (p == 0 && pf) {
                __builtin_amdgcn_global_load_lds((const AS1 void*)aptr[0],
                    (AS3 void*)(AnB + (wave * 4 + 0) * 1024), 16, 0, 0);
                __builtin_amdgcn_global_load_lds((const AS1 void*)aptr[1],
                    (AS3 void*)(AnB + (wave * 4 + 1) * 1024), 16, 0, 0);
                aptr[0] += 32; aptr[1] += 32;
            } else if (p == 1 && pf) {
                __builtin_amdgcn_global_load_lds((const AS1 void*)aptr[2],
                    (AS3 void*)(AnB + (wave * 4 + 2) * 1024), 16, 0, 0);
                __builtin_amdgcn_global_load_lds((const AS1 void*)aptr[3],
                    (AS3 void*)(AnB + (wave * 4 + 3) * 1024), 16, 0, 0);
                aptr[2] += 32; aptr[3] += 32;
            } else if (p == 2 && pf) {
                __builtin_amdgcn_global_load_lds((const AS1 void*)bptr[0],
                    (AS3 void*)(BnB + (wave * 2 + 0) * 1024), 16, 0, 0);
                __builtin_amdgcn_global_load_lds((const AS1 void*)bptr[1],
                    (AS3 void*)(BnB + (wave * 2 + 1) * 1024), 16, 0, 0);
                bptr[0] += 32; bptr[1] += 32;
            }

            asm volatile("s_barrier" ::: "memory");
            asm volatile("s_waitcnt lgkmcnt(0)" ::: "memory");
            __builtin_amdgcn_sched_barrier(0);       // rule #18

            if (p == 0) {
#pragma unroll
                for (int mf = 0; mf < 4; ++mf)
                    afr[mf] = cvt_f32x8_bf16(alo[mf], ahi[mf]);
            }

            __builtin_amdgcn_s_setprio(1);
#pragma unroll
            for (int mf = 0; mf < 4; ++mf) {
                acc[mf][2 * p] = __builtin_amdgcn_mfma_f32_16x16x32_bf16(
                    afr[mf], bfr[0], acc[mf][2 * p], 0, 0, 0);
                acc[mf][2 * p + 1] = __builtin_amdgcn_mfma_f32_16x16x32_bf16(
                    afr[mf], bfr[1], acc[mf][2 * p + 1], 0, 0, 0);
            }
            __builtin_amdgcn_s_setprio(0);

            // end of K-tile: counted wait -- drain tile t+1's 6 loads, keep
            // tile t+2's 6 in flight (vmcnt(0) only in the 2-tile tail).
            if (p == 3) {
                if (t < 30) asm volatile("s_waitcnt vmcnt(6)" ::: "memory");
                else        asm volatile("s_waitcnt vmcnt(0)" ::: "memory");
            }
            asm volatile("s_barrier" ::: "memory");
        }
        cur = (cur == 2) ? 0 : cur + 1;
    }

    // ---- epilogue: tanh(acc + qproj) * v, reduce over h, atomic into attn ----
    const int b = tileR >> 3;   // 8 row-tiles per batch (2048/256)
    float vv[8], qp[8];
#pragma unroll
    for (int nf = 0; nf < 8; ++nf) {
        int h  = h0 + wn * 128 + nf * 16 + c;
        vv[nf] = vvec[h];
        qp[nf] = qproj[b * HH + h];
    }
#pragma unroll
    for (int mf = 0; mf < 4; ++mf)
#pragma unroll
        for (int r = 0; r < 4; ++r) {
            float s = 0.0f;
#pragma unroll
            for (int nf = 0; nf < 8; ++nf)
                s += fast_tanh(acc[mf][nf][r] + qp[nf]) * vv[nf];
            // C/D layout: col = lane&15 (h), row = (lane>>4)*4 + reg (m row)
            s += __shfl_xor(s, 1);
            s += __shfl_xor(s, 2);
            s += __shfl_xor(s, 4);
            s += __shfl_xor(s, 8);
            if (c == 0)
                atomicAdd(attn + (r0 + wm * 64 + mf * 16 + g * 4 + r), s);
        }
}

// ---------------------------------------------------------------- softmax over M
__global__ __launch_bounds__(256) void softmax_kernel(const float* __restrict__ attn,
                                                      float* __restrict__ wout) {
    const int b = blockIdx.x, tid = threadIdx.x;
    __shared__ float red[8];
    float a[8];
    float mx = -1e30f;
#pragma unroll
    for (int i = 0; i < 8; ++i) {
        a[i] = attn[b * MM + i * 256 + tid];
        mx = fmaxf(mx, a[i]);
    }
#pragma unroll
    for (int off = 1; off < 64; off <<= 1) mx = fmaxf(mx, __shfl_xor(mx, off));
    if ((tid & 63) == 0) red[tid >> 6] = mx;
    __syncthreads();
    mx = fmaxf(fmaxf(red[0], red[1]), fmaxf(red[2], red[3]));
    float s = 0.0f;
#pragma unroll
    for (int i = 0; i < 8; ++i) {
        a[i] = __builtin_amdgcn_exp2f((a[i] - mx) * 1.4426950408889634f);
        s += a[i];
    }
#pragma unroll
    for (int off = 1; off < 64; off <<= 1) s += __shfl_xor(s, off);
    if ((tid & 63) == 0) red[4 + (tid >> 6)] = s;
    __syncthreads();
    s = red[4] + red[5] + red[6] + red[7];
    float inv = 1.0f / s;
#pragma unroll
    for (int i = 0; i < 8; ++i) wout[b * MM + i * 256 + tid] = a[i] * inv;
}

// ---------------------------------------------------------------- weighted memory
// out2[b,d] = sum_m w[b,m] * memory[b,m,d]; m split x16 (128 rows/block) for
// 4 blocks/CU latency hiding; float4 loads; atomic accumulate.
__global__ __launch_bounds__(256) void wmem_kernel(const float* __restrict__ mem,
                                                   const float* __restrict__ w,
                                                   float* __restrict__ out2) {
    const int m0 = blockIdx.x * 128;
    const int b  = blockIdx.y;
    __shared__ float wsh[128];
    if (threadIdx.x < 128) wsh[threadIdx.x] = w[b * MM + m0 + threadIdx.x];
    __syncthreads();
    const float4v* mp = (const float4v*)(mem + ((size_t)(b * MM + m0)) * DD)
                        + threadIdx.x;
    float4v acc = (float4v)0.0f;
#pragma unroll 8
    for (int m = 0; m < 128; ++m) {
        float wv = wsh[m];
        float4v x = mp[(size_t)m * 256];
        acc[0] = __builtin_fmaf(wv, x[0], acc[0]);
        acc[1] = __builtin_fmaf(wv, x[1], acc[1]);
        acc[2] = __builtin_fmaf(wv, x[2], acc[2]);
        acc[3] = __builtin_fmaf(wv, x[3], acc[3]);
    }
    float* o = out2 + b * DD + threadIdx.x * 4;
    atomicAdd(o + 0, acc[0]);
    atomicAdd(o + 1, acc[1]);
    atomicAdd(o + 2, acc[2]);
    atomicAdd(o + 3, acc[3]);
}

// ---------------------------------------------------------------- launcher
extern "C" void kernel_launch(void* const* d_in, const int* in_sizes, int n_in,
                              void* d_out, int out_size, void* d_ws, size_t ws_size,
                              hipStream_t stream) {
    const float* query  = (const float*)d_in[0];
    const float* memory = (const float*)d_in[1];
    const float* Wq     = (const float*)d_in[2];
    const float* bq     = (const float*)d_in[3];
    const float* Wm     = (const float*)d_in[4];
    const float* v      = (const float*)d_in[5];

    float* out      = (float*)d_out;
    float* wout     = out;                       // weights [64,1,2048]
    float* wmem_out = out + BSZ * MM;            // weighted_memory [64,1,1024]

    char*  ws    = (char*)d_ws;
    float* qproj = (float*)ws;                   // 256 KB
    float* attn  = (float*)(ws + 262144);        // 512 KB
    short* wmbf  = (short*)(ws + 786432);        // 2 MB  (total 2.75 MB of ws)

    static bool attr_done = false;
    if (!attr_done) {
        hipFuncSetAttribute((const void*)gemm_attn_kernel,
                            hipFuncAttributeMaxDynamicSharedMemorySize, 147456);
        attr_done = true;
    }

    hipMemsetAsync(attn, 0, (size_t)RR * sizeof(float), stream);
    hipMemsetAsync(d_out, 0, (size_t)out_size * sizeof(float), stream);

    cast_wm_kernel<<<HH * DD / (256 * 4), 256, 0, stream>>>(Wm, wmbf);
    qproj_kernel<<<dim3(HH / 256, BSZ), 256, 0, stream>>>(query, Wq, bq, qproj);
    gemm_attn_kernel<<<(RR / 256) * (HH / 256), 512, 147456, stream>>>(memory, wmbf, qproj, v, attn);
    softmax_kernel<<<BSZ, 256, 0, stream>>>(attn, wout);
    wmem_kernel<<<dim3(MM / 128, BSZ), 256, 0, stream>>>(memory, wout, wmem_out);
}